// Round 1
// baseline (1717.300 us; speedup 1.0000x reference)
//
#include <hip/hip_runtime.h>

// cRNN: B=512, T=2048, I=4, H=100, O=1
// out[b,t] = b_fc + W_fc . h_t ;  h_t = tanh(W_ih x_t + W_hh h_{t-1})
// One block (128 thr) per batch chain; W_hh row in regs; h in LDS (broadcast reads).

#define BB 512
#define TT 2048
#define II 4
#define HH 100

__global__ __launch_bounds__(128) void crnn_kernel(
    const float* __restrict__ x,     // [B,T,I]
    const float* __restrict__ W_ih,  // [H,I]
    const float* __restrict__ W_hh,  // [H,H]
    const float* __restrict__ W_fc,  // [O,H] = [1,100]
    const float* __restrict__ b_fc,  // [1]
    float* __restrict__ out)         // [B,T,1]
{
    __shared__ float xs[TT * II];          // 32 KB: x for this batch
    __shared__ float h_lds[128];           // h state (100 used), 16B aligned
    __shared__ float partial[2];

    const int tid  = threadIdx.x;
    const int b    = blockIdx.x;
    const int lane = tid & 63;
    const int wid  = tid >> 6;
    const int j    = tid;                  // output index this thread owns
    const int jj   = (j < HH) ? j : HH - 1; // clamp so no OOB weight reads

    // ---- stage x[b] (2048 float4) into LDS, coalesced ----
    const float4* xg = reinterpret_cast<const float4*>(x + (size_t)b * TT * II);
    float4* xl = reinterpret_cast<float4*>(xs);
#pragma unroll
    for (int it = 0; it < (TT * II / 4) / 128; ++it)
        xl[it * 128 + tid] = xg[it * 128 + tid];

    // ---- per-thread weights in registers ----
    float4 wih = reinterpret_cast<const float4*>(W_ih)[jj];
    float wr[HH];
    const float4* wrow = reinterpret_cast<const float4*>(W_hh + jj * HH);
#pragma unroll
    for (int k4 = 0; k4 < HH / 4; ++k4) {
        float4 v = wrow[k4];
        wr[4 * k4 + 0] = v.x; wr[4 * k4 + 1] = v.y;
        wr[4 * k4 + 2] = v.z; wr[4 * k4 + 3] = v.w;
    }
    const float wfc  = (j < HH) ? W_fc[j] : 0.f;
    const float bias = b_fc[0];

    h_lds[tid] = 0.f;                      // h_0 = 0
    __syncthreads();

    float* outb = out + (size_t)b * TT;
    const float4* h4  = reinterpret_cast<const float4*>(h_lds);
    const float4* xs4 = reinterpret_cast<const float4*>(xs);

    for (int t = 0; t < TT; ++t) {
        // input projection (broadcast x_t from LDS)
        float4 xv = xs4[t];
        float a0 = wih.x * xv.x;
        float a1 = wih.y * xv.y;
        float a2 = wih.z * xv.z;
        float a3 = wih.w * xv.w;
        // recurrent matvec: 100 FMAs, 4 independent chains
#pragma unroll
        for (int k4 = 0; k4 < HH / 4; ++k4) {
            float4 hv = h4[k4];            // broadcast read (no bank conflict)
            a0 = fmaf(wr[4 * k4 + 0], hv.x, a0);
            a1 = fmaf(wr[4 * k4 + 1], hv.y, a1);
            a2 = fmaf(wr[4 * k4 + 2], hv.z, a2);
            a3 = fmaf(wr[4 * k4 + 3], hv.w, a3);
        }
        float acc = (a0 + a1) + (a2 + a3);
        // tanh(acc) = 1 - 2/(exp(2 acc)+1); |acc| <= ~12 so no overflow
        float e  = __expf(2.f * acc);
        float hn = 1.f - 2.f / (e + 1.f);

        // output projection: reduce wfc*hn over j=0..99 (two waves)
        float c = (j < HH) ? wfc * hn : 0.f;
#pragma unroll
        for (int off = 32; off > 0; off >>= 1)
            c += __shfl_down(c, off, 64);

        __syncthreads();                   // all h reads for step t done
        if (j < HH) h_lds[j] = hn;
        if (lane == 0) partial[wid] = c;
        __syncthreads();                   // h_{t} + partials visible
        if (tid == 0) outb[t] = (partial[0] + partial[1]) + bias;
    }
}

extern "C" void kernel_launch(void* const* d_in, const int* in_sizes, int n_in,
                              void* d_out, int out_size, void* d_ws, size_t ws_size,
                              hipStream_t stream) {
    const float* x    = (const float*)d_in[0];
    const float* W_ih = (const float*)d_in[1];
    const float* W_hh = (const float*)d_in[2];
    const float* W_fc = (const float*)d_in[3];
    const float* b_fc = (const float*)d_in[4];
    float* out = (float*)d_out;
    crnn_kernel<<<BB, 128, 0, stream>>>(x, W_ih, W_hh, W_fc, b_fc, out);
}

// Round 2
// 1131.467 us; speedup vs baseline: 1.5178x; 1.5178x over previous
//
#include <hip/hip_runtime.h>

// cRNN: B=512, T=2048, I=4, H=100, O=1
// h_t = tanh(W_ih x_t + W_hh h_{t-1});  out[b,t] = W_fc.h_t + b_fc
// One block (128 thr, 2 waves) per batch chain.
// Serial loop does ONLY the recurrence (1 barrier/step); output projection is
// a parallel epilogue over a 64-step LDS history buffer.

#define BB 512
#define TT 2048
#define II 4
#define HH 100
#define HP 104              // padded row stride (float4-aligned)
#define CHUNK 64
#define NCH (TT / CHUNK)

__global__ __launch_bounds__(128, 1) void crnn_kernel(
    const float* __restrict__ x,     // [B,T,I]
    const float* __restrict__ W_ih,  // [H,I]
    const float* __restrict__ W_hh,  // [H,H]
    const float* __restrict__ W_fc,  // [1,H]
    const float* __restrict__ b_fc,  // [1]
    float* __restrict__ out)         // [B,T]
{
    __shared__ float xs[TT * II];              // 32 KB staged input
    __shared__ float hh[(CHUNK + 1) * HP];     // h history: row r = state after local step r-1
    __shared__ float wfcs[HP];                 // W_fc staged
    __shared__ float pt[2][CHUNK];             // epilogue partials

    const int tid = threadIdx.x;
    const int b   = blockIdx.x;
    const int j   = tid;
    const int jj  = (j < HH) ? j : HH - 1;

    // ---- stage x[b] into LDS (coalesced float4) ----
    const float4* xg = reinterpret_cast<const float4*>(x + (size_t)b * TT * II);
    float4* xl = reinterpret_cast<float4*>(xs);
#pragma unroll
    for (int it = 0; it < (TT * II / 4) / 128; ++it)
        xl[it * 128 + tid] = xg[it * 128 + tid];

    // ---- per-thread recurrent weights in registers ----
    float4 wih = reinterpret_cast<const float4*>(W_ih)[jj];
    float wr[HH];
    const float4* wrow = reinterpret_cast<const float4*>(W_hh + jj * HH);
#pragma unroll
    for (int k4 = 0; k4 < HH / 4; ++k4) {
        float4 v = wrow[k4];
        wr[4 * k4 + 0] = v.x; wr[4 * k4 + 1] = v.y;
        wr[4 * k4 + 2] = v.z; wr[4 * k4 + 3] = v.w;
    }
    if (tid < HP) wfcs[tid] = (tid < HH) ? W_fc[tid] : 0.f;
    const float bias = b_fc[0];
    if (tid < HP) hh[tid] = 0.f;               // h_0 = 0
    __syncthreads();

    float* outb = out + (size_t)b * TT;
    const float4* xs4 = reinterpret_cast<const float4*>(xs);

    for (int c = 0; c < NCH; ++c) {
        // ---- sequential recurrence over one chunk (1 barrier/step) ----
        for (int t = 0; t < CHUNK; ++t) {
            const float4* hrow = reinterpret_cast<const float4*>(hh + t * HP);
            float4 xv = xs4[c * CHUNK + t];
            float a0 = wih.x * xv.x;
            float a1 = wih.y * xv.y;
            float a2 = wih.z * xv.z;
            float a3 = wih.w * xv.w;
#pragma unroll
            for (int k4 = 0; k4 < HH / 4; ++k4) {
                float4 hv = hrow[k4];          // broadcast read
                a0 = fmaf(wr[4 * k4 + 0], hv.x, a0);
                a1 = fmaf(wr[4 * k4 + 1], hv.y, a1);
                a2 = fmaf(wr[4 * k4 + 2], hv.z, a2);
                a3 = fmaf(wr[4 * k4 + 3], hv.w, a3);
            }
            float acc = (a0 + a1) + (a2 + a3);
            float e   = __expf(2.f * acc);     // tanh = 1 - 2/(e^{2a}+1)
            float hn  = 1.f - 2.f / (e + 1.f);
            if (j < HH) hh[(t + 1) * HP + j] = hn;
            __syncthreads();
        }

        // ---- parallel output projection for the chunk ----
        const int tl = tid & (CHUNK - 1);      // output step within chunk
        const int kh = tid >> 6;               // K-half: 0 -> k[0,52), 1 -> k[52,100)
        const int k0  = kh ? 52 : 0;
        const int nk4 = kh ? 12 : 13;
        const float4* wf4 = reinterpret_cast<const float4*>(wfcs + k0);
        const float4* hr  = reinterpret_cast<const float4*>(hh + (tl + 1) * HP + k0);
        float csum = 0.f;
#pragma unroll
        for (int i = 0; i < 13; ++i) {
            if (i < nk4) {
                float4 hv = hr[i];
                float4 wv = wf4[i];
                csum = fmaf(hv.x, wv.x, csum);
                csum = fmaf(hv.y, wv.y, csum);
                csum = fmaf(hv.z, wv.z, csum);
                csum = fmaf(hv.w, wv.w, csum);
            }
        }
        pt[kh][tl] = csum;
        // carry state to row 0 for next chunk
        if (tid < HH) hh[tid] = hh[CHUNK * HP + tid];
        __syncthreads();
        if (tid < CHUNK) outb[c * CHUNK + tid] = (pt[0][tid] + pt[1][tid]) + bias;
    }
}

extern "C" void kernel_launch(void* const* d_in, const int* in_sizes, int n_in,
                              void* d_out, int out_size, void* d_ws, size_t ws_size,
                              hipStream_t stream) {
    const float* x    = (const float*)d_in[0];
    const float* W_ih = (const float*)d_in[1];
    const float* W_hh = (const float*)d_in[2];
    const float* W_fc = (const float*)d_in[3];
    const float* b_fc = (const float*)d_in[4];
    float* out = (float*)d_out;
    crnn_kernel<<<BB, 128, 0, stream>>>(x, W_ih, W_hh, W_fc, b_fc, out);
}

// Round 3
// 1103.551 us; speedup vs baseline: 1.5562x; 1.0253x over previous
//
#include <hip/hip_runtime.h>

// cRNN: B=512, T=2048, I=4, H=100, O=1
// h_t = tanh(W_ih x_t + W_hh h_{t-1});  out[b,t] = W_fc.h_t + b_fc
// One block (128 thr, 2 waves) per batch chain. Serial loop: preload full h
// row into 100 VGPRs (25x ds_read_b128), one wait, 100 stall-free FMAs,
// 1 barrier/step. Output projection amortized over a 64-step LDS history.

#define BB 512
#define TT 2048
#define II 4
#define HH 100
#define HP 104              // padded row stride (float4-aligned; pad zeroed)
#define CHUNK 64
#define NCH (TT / CHUNK)

__global__ __launch_bounds__(128, 1) void crnn_kernel(
    const float* __restrict__ x,     // [B,T,I]
    const float* __restrict__ W_ih,  // [H,I]
    const float* __restrict__ W_hh,  // [H,H]
    const float* __restrict__ W_fc,  // [1,H]
    const float* __restrict__ b_fc,  // [1]
    float* __restrict__ out)         // [B,T]
{
    __shared__ float xs[TT * II];              // 32 KB staged input
    __shared__ float hh[(CHUNK + 1) * HP];     // h history rows
    __shared__ float wfcs[HP];                 // W_fc staged (zero-padded)
    __shared__ float pt[2][CHUNK];             // epilogue partials

    const int tid = threadIdx.x;
    const int b   = blockIdx.x;
    const int j   = tid;
    const int jj  = (j < HH) ? j : HH - 1;
    const bool active = (j < HH);

    // ---- stage x[b] into LDS (coalesced float4) ----
    const float4* xg = reinterpret_cast<const float4*>(x + (size_t)b * TT * II);
    float4* xl = reinterpret_cast<float4*>(xs);
#pragma unroll
    for (int it = 0; it < (TT * II / 4) / 128; ++it)
        xl[it * 128 + tid] = xg[it * 128 + tid];

    // ---- per-thread recurrent weights in registers ----
    float4 wih = reinterpret_cast<const float4*>(W_ih)[jj];
    float wr[HH];
    const float4* wrow = reinterpret_cast<const float4*>(W_hh + jj * HH);
#pragma unroll
    for (int k4 = 0; k4 < HH / 4; ++k4) {
        float4 v = wrow[k4];
        wr[4 * k4 + 0] = v.x; wr[4 * k4 + 1] = v.y;
        wr[4 * k4 + 2] = v.z; wr[4 * k4 + 3] = v.w;
    }
    if (tid < HP) wfcs[tid] = (tid < HH) ? W_fc[tid] : 0.f;
    const float bias = b_fc[0];
    // zero h_0 row and ALL row pads (cols 100..103) once
    if (tid < HP) hh[tid] = 0.f;
    for (int i = tid; i < (CHUNK + 1) * 4; i += 128) {
        int r = i >> 2, p = i & 3;
        hh[r * HP + HH + p] = 0.f;
    }
    __syncthreads();

    float* outb = out + (size_t)b * TT;
    const float4* xs4 = reinterpret_cast<const float4*>(xs);

    for (int c = 0; c < NCH; ++c) {
        // ---- sequential recurrence over one chunk (1 barrier/step) ----
        for (int t = 0; t < CHUNK; ++t) {
            const float4* hrow = reinterpret_cast<const float4*>(hh + t * HP);
            // preload the ENTIRE h row into registers (independent reads,
            // single wait), then run the FMA stream with zero LDS stalls
            float4 hv[HH / 4];
#pragma unroll
            for (int k4 = 0; k4 < HH / 4; ++k4) hv[k4] = hrow[k4];
            float4 xv = xs4[c * CHUNK + t];

            float a0 = wih.x * xv.x;
            float a1 = wih.y * xv.y;
            float a2 = wih.z * xv.z;
            float a3 = wih.w * xv.w;
#pragma unroll
            for (int k4 = 0; k4 < HH / 4; ++k4) {
                a0 = fmaf(wr[4 * k4 + 0], hv[k4].x, a0);
                a1 = fmaf(wr[4 * k4 + 1], hv[k4].y, a1);
                a2 = fmaf(wr[4 * k4 + 2], hv[k4].z, a2);
                a3 = fmaf(wr[4 * k4 + 3], hv[k4].w, a3);
            }
            float acc = (a0 + a1) + (a2 + a3);
            // tanh(acc) = 1 - 2/(exp(2 acc)+1)
            float e  = __expf(2.f * acc);
            float hn = 1.f - 2.f * __builtin_amdgcn_rcpf(e + 1.f);
            if (active) hh[(t + 1) * HP + j] = hn;
            __syncthreads();
        }

        // ---- parallel output projection for the chunk (branch-free) ----
        const int tl = tid & (CHUNK - 1);      // step within chunk
        const int kh = tid >> 6;               // K-half
        const int k0 = kh * 52;                // 0..51 / 52..103 (pad zeroed)
        const float4* wf4 = reinterpret_cast<const float4*>(wfcs + k0);
        const float4* hr  = reinterpret_cast<const float4*>(hh + (tl + 1) * HP + k0);
        float csum = 0.f;
#pragma unroll
        for (int i = 0; i < 13; ++i) {
            float4 hvv = hr[i];
            float4 wv  = wf4[i];
            csum = fmaf(hvv.x, wv.x, csum);
            csum = fmaf(hvv.y, wv.y, csum);
            csum = fmaf(hvv.z, wv.z, csum);
            csum = fmaf(hvv.w, wv.w, csum);
        }
        pt[kh][tl] = csum;
        // carry state to row 0 for next chunk (pad cols stay 0)
        if (tid < HH) hh[tid] = hh[CHUNK * HP + tid];
        __syncthreads();
        if (tid < CHUNK) outb[c * CHUNK + tid] = (pt[0][tid] + pt[1][tid]) + bias;
        __syncthreads();
    }
}

extern "C" void kernel_launch(void* const* d_in, const int* in_sizes, int n_in,
                              void* d_out, int out_size, void* d_ws, size_t ws_size,
                              hipStream_t stream) {
    const float* x    = (const float*)d_in[0];
    const float* W_ih = (const float*)d_in[1];
    const float* W_hh = (const float*)d_in[2];
    const float* W_fc = (const float*)d_in[3];
    const float* b_fc = (const float*)d_in[4];
    float* out = (float*)d_out;
    crnn_kernel<<<BB, 128, 0, stream>>>(x, W_ih, W_hh, W_fc, b_fc, out);
}

// Round 4
// 962.557 us; speedup vs baseline: 1.7841x; 1.1465x over previous
//
#include <hip/hip_runtime.h>

// cRNN: B=512, T=2048, I=4, H=100, O=1
// h_t = tanh(W_ih x_t + W_hh h_{t-1});  out[b,t] = W_fc.h_t + b_fc
// One block (128 thr, 2 waves) per chain. h lives in lane registers; the
// 100-wide broadcast is done with v_readlane (VALU pipe) instead of LDS
// reads (the round-3 bottleneck: 100 broadcast ds_read_b128/CU-step = ~1200
// cyc on the per-CU LDS pipe). Per step: 1 ds_write_b32 + 1 barrier +
// 1 ds_read_b32. Output projection amortized over a 64-step history.

#define BB 512
#define TT 2048
#define II 4
#define HH 100
#define HP 116              // history row stride (float4-aligned, 4-way-ish banks)
#define CHUNK 64
#define NCH (TT / CHUNK)

__device__ __forceinline__ float rlf(float v, int l) {
    return __int_as_float(__builtin_amdgcn_readlane(__float_as_int(v), l));
}

__global__ __launch_bounds__(128, 1) void crnn_kernel(
    const float* __restrict__ x,     // [B,T,I]
    const float* __restrict__ W_ih,  // [H,I]
    const float* __restrict__ W_hh,  // [H,H]
    const float* __restrict__ W_fc,  // [1,H]
    const float* __restrict__ b_fc,  // [1]
    float* __restrict__ out)         // [B,T]
{
    __shared__ float xs[TT * II];          // 32 KB staged input
    __shared__ float hh[CHUNK * HP];       // ~29 KB: h history / exchange rows
    __shared__ float wfcs[HP];
    __shared__ float pt[2][CHUNK];

    const int tid  = threadIdx.x;
    const int b    = blockIdx.x;
    const int lane = tid & 63;
    const int w    = tid >> 6;
    const int j    = tid;                  // owned output index
    const int jj   = (j < HH) ? j : HH - 1;
    const bool act = (j < HH);

    // ---- stage x[b] into LDS (coalesced float4) ----
    const float4* xg = reinterpret_cast<const float4*>(x + (size_t)b * TT * II);
    float4* xl = reinterpret_cast<float4*>(xs);
#pragma unroll
    for (int it = 0; it < (TT * II / 4) / 128; ++it)
        xl[it * 128 + tid] = xg[it * 128 + tid];

    // ---- per-thread weights in registers ----
    float4 wih = reinterpret_cast<const float4*>(W_ih)[jj];
    float wr[HH];
    const float4* wrow = reinterpret_cast<const float4*>(W_hh + jj * HH);
#pragma unroll
    for (int k4 = 0; k4 < HH / 4; ++k4) {
        float4 v = wrow[k4];
        wr[4 * k4 + 0] = v.x; wr[4 * k4 + 1] = v.y;
        wr[4 * k4 + 2] = v.z; wr[4 * k4 + 3] = v.w;
    }
    if (tid < HP) wfcs[tid] = (tid < HH) ? W_fc[tid] : 0.f;
    const float bias = b_fc[0];
    // zero the pad columns (HH..HP-1) of all history rows, once
    for (int i = tid; i < CHUNK * (HP - HH); i += 128) {
        int r = i / (HP - HH), p = i % (HP - HH);
        hh[r * HP + HH + p] = 0.f;
    }
    __syncthreads();

    // constant per-lane exchange-read offset within a row:
    // W0 fetches h[64..99] (lanes 0..35), W1 fetches h[0..63]
    const int voff = w ? lane : (64 + (lane < 36 ? lane : 35));

    float vh = 0.f;                        // own h (h_0 = 0)
    float vo = 0.f;                        // other wave's h values, by lane
    float* outb = out + (size_t)b * TT;

    for (int c = 0; c < NCH; ++c) {
        const float4* xs4 = reinterpret_cast<const float4*>(xs) + c * CHUNK;
        for (int t = 0; t < CHUNK; ++t) {
            float4 xv = xs4[t];
            float a0 = wih.x * xv.x;
            float a1 = wih.y * xv.y;
            float a2 = wih.z * xv.z;
            float a3 = wih.w * xv.w;
            if (w == 0) {
                // own half first (vh = h[lane]), vo half last (hides its load)
#pragma unroll
                for (int k = 0; k < 64; k += 4) {
                    a0 = fmaf(wr[k + 0], rlf(vh, k + 0), a0);
                    a1 = fmaf(wr[k + 1], rlf(vh, k + 1), a1);
                    a2 = fmaf(wr[k + 2], rlf(vh, k + 2), a2);
                    a3 = fmaf(wr[k + 3], rlf(vh, k + 3), a3);
                }
#pragma unroll
                for (int k = 64; k < 100; k += 4) {
                    a0 = fmaf(wr[k + 0], rlf(vo, k - 64 + 0), a0);
                    a1 = fmaf(wr[k + 1], rlf(vo, k - 64 + 1), a1);
                    a2 = fmaf(wr[k + 2], rlf(vo, k - 64 + 2), a2);
                    a3 = fmaf(wr[k + 3], rlf(vo, k - 64 + 3), a3);
                }
            } else {
                // W1 owns h[64..99] in lanes 0..35; consume own half first
#pragma unroll
                for (int k = 64; k < 100; k += 4) {
                    a0 = fmaf(wr[k + 0], rlf(vh, k - 64 + 0), a0);
                    a1 = fmaf(wr[k + 1], rlf(vh, k - 64 + 1), a1);
                    a2 = fmaf(wr[k + 2], rlf(vh, k - 64 + 2), a2);
                    a3 = fmaf(wr[k + 3], rlf(vh, k - 64 + 3), a3);
                }
#pragma unroll
                for (int k = 0; k < 64; k += 4) {
                    a0 = fmaf(wr[k + 0], rlf(vo, k + 0), a0);
                    a1 = fmaf(wr[k + 1], rlf(vo, k + 1), a1);
                    a2 = fmaf(wr[k + 2], rlf(vo, k + 2), a2);
                    a3 = fmaf(wr[k + 3], rlf(vo, k + 3), a3);
                }
            }
            float acc = (a0 + a1) + (a2 + a3);
            float e   = __expf(2.f * acc);         // tanh = 1 - 2/(e^{2a}+1)
            float hn  = 1.f - 2.f * __builtin_amdgcn_rcpf(e + 1.f);
            vh = hn;
            float* rowW = hh + t * HP;
            if (act) rowW[j] = hn;                 // history + exchange
            __syncthreads();
            vo = rowW[voff];                       // other half for next step
        }

        // ---- amortized output projection over the 64-row history ----
        const int tl = tid & (CHUNK - 1);
        const int kh = tid >> 6;
        const int k0 = kh * 52;                    // halves: 0..51 / 52..103 (pads 0)
        const float4* wf4 = reinterpret_cast<const float4*>(wfcs + k0);
        const float4* hr  = reinterpret_cast<const float4*>(hh + tl * HP + k0);
        float csum = 0.f;
#pragma unroll
        for (int i = 0; i < 13; ++i) {
            float4 hvv = hr[i];
            float4 wv  = wf4[i];
            csum = fmaf(hvv.x, wv.x, csum);
            csum = fmaf(hvv.y, wv.y, csum);
            csum = fmaf(hvv.z, wv.z, csum);
            csum = fmaf(hvv.w, wv.w, csum);
        }
        pt[kh][tl] = csum;
        __syncthreads();                            // history reads + pt done
        if (tid < CHUNK) outb[c * CHUNK + tid] = (pt[0][tid] + pt[1][tid]) + bias;
    }
}

extern "C" void kernel_launch(void* const* d_in, const int* in_sizes, int n_in,
                              void* d_out, int out_size, void* d_ws, size_t ws_size,
                              hipStream_t stream) {
    const float* x    = (const float*)d_in[0];
    const float* W_ih = (const float*)d_in[1];
    const float* W_hh = (const float*)d_in[2];
    const float* W_fc = (const float*)d_in[3];
    const float* b_fc = (const float*)d_in[4];
    float* out = (float*)d_out;
    crnn_kernel<<<BB, 128, 0, stream>>>(x, W_ih, W_hh, W_fc, b_fc, out);
}